// Round 8
// baseline (115.582 us; speedup 1.0000x reference)
//
#include <hip/hip_runtime.h>
#include <hip/hip_bf16.h>
#include <stdint.h>

#define H 512
#define W 512
#define HW (H * W)
#define TR 16             // core rows per k_sal block
#define NSTRIP (H / TR)   // 32 strips per image (k_sal)
#define NSLOT (TR + 2)    // core + 2 halo rows
#define LSTR 520          // 4 pad + 512 + 4 pad bytes per LDS row

__device__ __forceinline__ int refl(int i, int n) {
    // BORDER_REFLECT_101: -1 -> 1, n -> n-2
    return i < 0 ? -i : (i >= n ? 2 * n - 2 - i : i);
}

// 10 stencil columns (x0-1 .. x0+8) from a 16-byte window starting at x0-4.
__device__ __forceinline__ void cols10(uint2 lo, uint2 hi, float* __restrict__ c) {
    c[0] = (float)(lo.x >> 24);
    c[1] = (float)(lo.y & 0xffu);
    c[2] = (float)((lo.y >> 8) & 0xffu);
    c[3] = (float)((lo.y >> 16) & 0xffu);
    c[4] = (float)(lo.y >> 24);
    c[5] = (float)(hi.x & 0xffu);
    c[6] = (float)((hi.x >> 8) & 0xffu);
    c[7] = (float)((hi.x >> 16) & 0xffu);
    c[8] = (float)(hi.x >> 24);
    c[9] = (float)(hi.y & 0xffu);
}

// ---------------- K1: fused gray + sobel + per-strip min/max + q emit ----------------
// block = 256 threads, owns 16 rows of ONE source of one image (18-row halo load,
// 12.5% halo tax vs 25% at TR=8). Register-double-buffered staging.
__global__ __launch_bounds__(256) void k_sal(const float* __restrict__ vis,
                                             const float* __restrict__ ir,
                                             uint8_t* __restrict__ qvis,
                                             uint8_t* __restrict__ qir,
                                             float* __restrict__ pm, int B) {
    __shared__ uint8_t g[NSLOT][LSTR];
    __shared__ float red[4][2];
    int tid = threadIdx.x;
    int per_src = B * NSTRIP;            // 512
    int blk = blockIdx.x;
    int src = blk >= per_src;
    int rem = src ? blk - per_src : blk;
    int b     = rem >> 5;                // 32 strips per image
    int strip = rem & 31;
    int y0 = strip * TR;

    const float4* p4 = (const float4*)((src ? ir : vis) + (size_t)b * 3 * HW);
    uint8_t* q = (src ? qir : qvis) + (size_t)b * HW;

    // Phase 1: 18 rows x 128 segs = 2304 tasks; 9 triples/thread, 2-deep pipeline.
    float4 Rc, Gc, Bc, Rn, Gn, Bn;
    {
        int t = tid, j = t >> 7, seg = t & 127;
        int row = refl(y0 - 1 + j, H);
        int o = row * (W / 4) + seg;
        Rc = p4[o];
        Gc = p4[o + HW / 4];
        Bc = p4[o + 2 * (HW / 4)];
    }
    #pragma unroll
    for (int it = 0; it < 9; ++it) {
        if (it < 8) {
            int t = tid + (it + 1) * 256, j = t >> 7, seg = t & 127;
            int row = refl(y0 - 1 + j, H);
            int o = row * (W / 4) + seg;
            Rn = p4[o];
            Gn = p4[o + HW / 4];
            Bn = p4[o + 2 * (HW / 4)];
        }
        __builtin_amdgcn_sched_barrier(0);
        {
            int t = tid + it * 256, j = t >> 7, seg = t & 127;
            uchar4 qq;
            qq.x = (uint8_t)((0.2989f * Rc.x + 0.587f * Gc.x + 0.114f * Bc.x) * 255.0f);
            qq.y = (uint8_t)((0.2989f * Rc.y + 0.587f * Gc.y + 0.114f * Bc.y) * 255.0f);
            qq.z = (uint8_t)((0.2989f * Rc.z + 0.587f * Gc.z + 0.114f * Bc.z) * 255.0f);
            qq.w = (uint8_t)((0.2989f * Rc.w + 0.587f * Gc.w + 0.114f * Bc.w) * 255.0f);
            *(uchar4*)&g[j][4 + seg * 4] = qq;
        }
        Rc = Rn; Gc = Gn; Bc = Bn;
    }
    __syncthreads();
    // reflect-101 column pads: byte 3 is x=-1 -> gray[1]; byte 516 is x=512 -> gray[510]
    if (tid < NSLOT) {
        g[tid][3]   = g[tid][5];    // 4+1
        g[tid][516] = g[tid][514];  // 4+510
    }
    __syncthreads();

    // Phase 2: sobel on 16 core rows: 16 x 64 segs = 1024 tasks; 4/thread.
    float mn = INFINITY, mx = 0.0f;
    #pragma unroll
    for (int k = 0; k < 4; ++k) {
        int task = tid + k * 256;
        int r  = task >> 6;   // 0..15 -> slots r, r+1, r+2 (center row y0+r)
        int s8 = task & 63;   // 8-px segment
        const uint8_t* rp0 = &g[r][s8 * 8];
        const uint8_t* rp1 = &g[r + 1][s8 * 8];
        const uint8_t* rp2 = &g[r + 2][s8 * 8];
        uint2 a0 = *(const uint2*)rp0, b0 = *(const uint2*)(rp0 + 8);
        uint2 a1 = *(const uint2*)rp1, b1 = *(const uint2*)(rp1 + 8);
        uint2 a2 = *(const uint2*)rp2, b2 = *(const uint2*)(rp2 + 8);
        uint2 qw; qw.x = a1.y; qw.y = b1.x;
        *(uint2*)(q + (size_t)(y0 + r) * W + s8 * 8) = qw;
        float c0[10], c1[10], c2[10];
        cols10(a0, b0, c0);
        cols10(a1, b1, c1);
        cols10(a2, b2, c2);
        float sx[10], sy[10];
        #pragma unroll
        for (int j = 0; j < 10; ++j) {
            sx[j] = c0[j] + 2.0f * c1[j] + c2[j];
            sy[j] = c2[j] - c0[j];
        }
        #pragma unroll
        for (int p = 0; p < 8; ++p) {
            float gx = sx[p + 2] - sx[p];
            float gy = sy[p] + 2.0f * sy[p + 1] + sy[p + 2];
            float m = sqrtf(gx * gx + gy * gy);
            mn = fminf(mn, m);
            mx = fmaxf(mx, m);
        }
    }

    // block reduce + plain store (no atomics)
    #pragma unroll
    for (int o = 32; o > 0; o >>= 1) {
        mn = fminf(mn, __shfl_down(mn, o));
        mx = fmaxf(mx, __shfl_down(mx, o));
    }
    int lane = tid & 63, w = tid >> 6;
    if (lane == 0) { red[w][0] = mn; red[w][1] = mx; }
    __syncthreads();
    if (tid == 0) {
        #pragma unroll
        for (int ww = 1; ww < 4; ++ww) {
            mn = fminf(mn, red[ww][0]);
            mx = fmaxf(mx, red[ww][1]);
        }
        float* o = pm + ((size_t)(src * B + b) * NSTRIP + strip) * 2;
        o[0] = mn;
        o[1] = mx;
    }
}

// Extract this lane's 10 stencil columns from an 8-byte row segment via shuffles.
__device__ __forceinline__ void row_cols(uint2 v, int lane, float* __restrict__ c) {
    uint32_t lx = __shfl_up(v.y, 1);
    uint32_t rx = __shfl_down(v.x, 1);
    uint32_t lb = (lane == 0)  ? ((v.x >> 8) & 0xffu)  : (lx >> 24);
    uint32_t rb = (lane == 63) ? ((v.y >> 16) & 0xffu) : (rx & 0xffu);
    c[0] = (float)lb;
    c[1] = (float)(v.x & 0xffu);
    c[2] = (float)((v.x >> 8) & 0xffu);
    c[3] = (float)((v.x >> 16) & 0xffu);
    c[4] = (float)(v.x >> 24);
    c[5] = (float)(v.y & 0xffu);
    c[6] = (float)((v.y >> 8) & 0xffu);
    c[7] = (float)((v.y >> 16) & 0xffu);
    c[8] = (float)(v.y >> 24);
    c[9] = (float)rb;
}

__device__ __forceinline__ void sobel_row8(const uint8_t* __restrict__ q, int y, int lane,
                                           float* __restrict__ mag) {
    const uint2* rm = (const uint2*)(q + (size_t)refl(y - 1, H) * W);
    const uint2* r0 = (const uint2*)(q + (size_t)y * W);
    const uint2* rp = (const uint2*)(q + (size_t)refl(y + 1, H) * W);
    uint2 vm = rm[lane], v0 = r0[lane], vp = rp[lane];
    float c0[10], c1[10], c2[10];
    row_cols(vm, lane, c0);
    row_cols(v0, lane, c1);
    row_cols(vp, lane, c2);
    float sx[10], sy[10];
    #pragma unroll
    for (int j = 0; j < 10; ++j) {
        sx[j] = c0[j] + 2.0f * c1[j] + c2[j];
        sy[j] = c2[j] - c0[j];
    }
    #pragma unroll
    for (int k = 0; k < 8; ++k) {
        float gx = sx[k + 2] - sx[k];
        float gy = sy[k] + 2.0f * sy[k + 1] + sy[k + 2];
        mag[k] = sqrtf(gx * gx + gy * gy);
    }
}

// ---------------- K2: minmax finalize + blend + |diff| + last-block final reduce ------
// block = 4 waves over 8 rows of image b. Last finishing block reduces all partials.
__global__ __launch_bounds__(256) void k_loss(const float* __restrict__ vis,
                                              const float* __restrict__ ir,
                                              const float* __restrict__ fus,
                                              const uint8_t* __restrict__ qvis,
                                              const uint8_t* __restrict__ qir,
                                              const float* __restrict__ pm,
                                              float* __restrict__ partial,
                                              uint32_t* __restrict__ counter,
                                              float* __restrict__ out,
                                              int B, int nblk, long long N) {
    int w = threadIdx.x >> 6, lane = threadIdx.x & 63;
    int b = blockIdx.x >> 6;
    int y0 = (blockIdx.x & 63) * 8;

    __shared__ float sred[4];
    {
        // finalize per-image min/max from 32 per-strip partials (lane&31: dups ok)
        int src = w >> 1, qsel = w & 1;
        float v = pm[((size_t)(src * B + b) * NSTRIP + (lane & 31)) * 2 + qsel];
        if (qsel == 0) {
            #pragma unroll
            for (int o = 32; o > 0; o >>= 1) v = fminf(v, __shfl_down(v, o));
        } else {
            #pragma unroll
            for (int o = 32; o > 0; o >>= 1) v = fmaxf(v, __shfl_down(v, o));
        }
        if (lane == 0) sred[w] = v;
    }
    __syncthreads();
    float mn_v = sred[0], mx_v = sred[1], mn_i = sred[2], mx_i = sred[3];
    float inv_v = 1.0f / fmaxf(mx_v - mn_v, 1e-8f);
    float inv_i = 1.0f / fmaxf(mx_i - mn_i, 1e-8f);

    float acc = 0.0f;
    #pragma unroll
    for (int rr = 0; rr < 2; ++rr) {
        int y = y0 + w + rr * 4;
        float mv[8], mi[8];
        sobel_row8(qvis + (size_t)b * HW, y, lane, mv);
        sobel_row8(qir  + (size_t)b * HW, y, lane, mi);

        float wv[8], wi[8];
        #pragma unroll
        for (int k = 0; k < 8; ++k) {
            float sv = (mv[k] - mn_v) * inv_v;
            float si = (mi[k] - mn_i) * inv_i;
            float den = sv + si + 1e-8f;
            float rden = 1.0f / den;
            wv[k] = sv * rden;
            wi[k] = si * rden;
        }

        int i = y * W + lane * 8;
        #pragma unroll
        for (int ch = 0; ch < 3; ++ch) {
            size_t e4 = ((((size_t)b * 3 + ch) * HW) + i) >> 2;
            const float4* v4 = (const float4*)vis;
            const float4* r4 = (const float4*)ir;
            const float4* f4 = (const float4*)fus;
            float4 va = v4[e4], vb = v4[e4 + 1];
            float4 ra = r4[e4], rb = r4[e4 + 1];
            float4 fa = f4[e4], fb = f4[e4 + 1];
            acc += fabsf(wv[0] * va.x + wi[0] * ra.x - fa.x);
            acc += fabsf(wv[1] * va.y + wi[1] * ra.y - fa.y);
            acc += fabsf(wv[2] * va.z + wi[2] * ra.z - fa.z);
            acc += fabsf(wv[3] * va.w + wi[3] * ra.w - fa.w);
            acc += fabsf(wv[4] * vb.x + wi[4] * rb.x - fb.x);
            acc += fabsf(wv[5] * vb.y + wi[5] * rb.y - fb.y);
            acc += fabsf(wv[6] * vb.z + wi[6] * rb.z - fb.z);
            acc += fabsf(wv[7] * vb.w + wi[7] * rb.w - fb.w);
        }
    }

    #pragma unroll
    for (int o = 32; o > 0; o >>= 1) acc += __shfl_down(acc, o);
    __shared__ float ssum[4];
    __shared__ int is_last;
    if (lane == 0) ssum[w] = acc;
    __syncthreads();
    if (threadIdx.x == 0) {
        float blocksum = ssum[0] + ssum[1] + ssum[2] + ssum[3];
        // agent-scope store so the last block sees it across XCDs
        __hip_atomic_store(&partial[blockIdx.x], blocksum,
                           __ATOMIC_RELEASE, __HIP_MEMORY_SCOPE_AGENT);
        uint32_t old = __hip_atomic_fetch_add(counter, 1u,
                           __ATOMIC_ACQ_REL, __HIP_MEMORY_SCOPE_AGENT);
        is_last = (old == (uint32_t)(nblk - 1));
    }
    __syncthreads();
    if (is_last) {
        // final reduce: 256 threads over nblk partials (nblk = 1024)
        double s = 0.0;
        for (int i = threadIdx.x; i < nblk; i += 256) {
            float p = __hip_atomic_load(&partial[i],
                         __ATOMIC_ACQUIRE, __HIP_MEMORY_SCOPE_AGENT);
            s += (double)p;
        }
        __shared__ double sm[256];
        sm[threadIdx.x] = s;
        __syncthreads();
        for (int k = 128; k > 0; k >>= 1) {
            if (threadIdx.x < k) sm[threadIdx.x] += sm[threadIdx.x + k];
            __syncthreads();
        }
        if (threadIdx.x == 0) out[0] = (float)(sm[0] / (double)N);
    }
}

extern "C" void kernel_launch(void* const* d_in, const int* in_sizes, int n_in,
                              void* d_out, int out_size, void* d_ws, size_t ws_size,
                              hipStream_t stream) {
    const float* vis = (const float*)d_in[0];
    const float* ir  = (const float*)d_in[1];
    const float* fus = (const float*)d_in[2];
    int B = in_sizes[0] / (3 * HW);  // 16

    uint8_t* qvis = (uint8_t*)d_ws;
    uint8_t* qir  = qvis + (size_t)B * HW;
    float* pm      = (float*)(qir + (size_t)B * HW);       // 2*B*32*2 floats
    float* partial = pm + (size_t)2 * B * NSTRIP * 2;      // 1024 floats
    uint32_t* counter = (uint32_t*)(partial + 1024);
    float* out = (float*)d_out;

    hipMemsetAsync(counter, 0, sizeof(uint32_t), stream);

    int nblk_sal = 2 * B * NSTRIP;   // 1024 blocks (one source, 16-row strip each)
    k_sal<<<nblk_sal, 256, 0, stream>>>(vis, ir, qvis, qir, pm, B);

    int nblk_loss = B * (H / 8);     // 1024 blocks
    k_loss<<<nblk_loss, 256, 0, stream>>>(vis, ir, fus, qvis, qir, pm, partial,
                                          counter, out, B, nblk_loss,
                                          (long long)B * 3 * HW);
}

// Round 9
// 54.991 us; speedup vs baseline: 2.1018x; 2.1018x over previous
//
#include <hip/hip_runtime.h>
#include <hip/hip_bf16.h>
#include <stdint.h>

#define H 512
#define W 512
#define HW (H * W)
#define TR 16             // core rows per k_sal block
#define NSTRIP (H / TR)   // 32 strips per image (k_sal)
#define NSLOT (TR + 2)    // core + 2 halo rows
#define LSTR 520          // 4 pad + 512 + 4 pad bytes per LDS row

__device__ __forceinline__ int refl(int i, int n) {
    // BORDER_REFLECT_101: -1 -> 1, n -> n-2
    return i < 0 ? -i : (i >= n ? 2 * n - 2 - i : i);
}

// 10 stencil columns (x0-1 .. x0+8) from a 16-byte window starting at x0-4.
__device__ __forceinline__ void cols10(uint2 lo, uint2 hi, float* __restrict__ c) {
    c[0] = (float)(lo.x >> 24);
    c[1] = (float)(lo.y & 0xffu);
    c[2] = (float)((lo.y >> 8) & 0xffu);
    c[3] = (float)((lo.y >> 16) & 0xffu);
    c[4] = (float)(lo.y >> 24);
    c[5] = (float)(hi.x & 0xffu);
    c[6] = (float)((hi.x >> 8) & 0xffu);
    c[7] = (float)((hi.x >> 16) & 0xffu);
    c[8] = (float)(hi.x >> 24);
    c[9] = (float)(hi.y & 0xffu);
}

// ---------------- K1: fused gray + sobel + per-strip min/max + q emit ----------------
// block = 256 threads, owns 16 rows of ONE source of one image (18-row halo load,
// 12.5% halo tax). Register-double-buffered staging.
__global__ __launch_bounds__(256) void k_sal(const float* __restrict__ vis,
                                             const float* __restrict__ ir,
                                             uint8_t* __restrict__ qvis,
                                             uint8_t* __restrict__ qir,
                                             float* __restrict__ pm, int B) {
    __shared__ uint8_t g[NSLOT][LSTR];
    __shared__ float red[4][2];
    int tid = threadIdx.x;
    int per_src = B * NSTRIP;            // 512
    int blk = blockIdx.x;
    int src = blk >= per_src;
    int rem = src ? blk - per_src : blk;
    int b     = rem >> 5;                // 32 strips per image
    int strip = rem & 31;
    int y0 = strip * TR;

    const float4* p4 = (const float4*)((src ? ir : vis) + (size_t)b * 3 * HW);
    uint8_t* q = (src ? qir : qvis) + (size_t)b * HW;

    // Phase 1: 18 rows x 128 segs = 2304 tasks; 9 triples/thread, 2-deep pipeline.
    float4 Rc, Gc, Bc, Rn, Gn, Bn;
    {
        int t = tid, j = t >> 7, seg = t & 127;
        int row = refl(y0 - 1 + j, H);
        int o = row * (W / 4) + seg;
        Rc = p4[o];
        Gc = p4[o + HW / 4];
        Bc = p4[o + 2 * (HW / 4)];
    }
    #pragma unroll
    for (int it = 0; it < 9; ++it) {
        if (it < 8) {
            int t = tid + (it + 1) * 256, j = t >> 7, seg = t & 127;
            int row = refl(y0 - 1 + j, H);
            int o = row * (W / 4) + seg;
            Rn = p4[o];
            Gn = p4[o + HW / 4];
            Bn = p4[o + 2 * (HW / 4)];
        }
        __builtin_amdgcn_sched_barrier(0);
        {
            int t = tid + it * 256, j = t >> 7, seg = t & 127;
            uchar4 qq;
            qq.x = (uint8_t)((0.2989f * Rc.x + 0.587f * Gc.x + 0.114f * Bc.x) * 255.0f);
            qq.y = (uint8_t)((0.2989f * Rc.y + 0.587f * Gc.y + 0.114f * Bc.y) * 255.0f);
            qq.z = (uint8_t)((0.2989f * Rc.z + 0.587f * Gc.z + 0.114f * Bc.z) * 255.0f);
            qq.w = (uint8_t)((0.2989f * Rc.w + 0.587f * Gc.w + 0.114f * Bc.w) * 255.0f);
            *(uchar4*)&g[j][4 + seg * 4] = qq;
        }
        Rc = Rn; Gc = Gn; Bc = Bn;
    }
    __syncthreads();
    // reflect-101 column pads: byte 3 is x=-1 -> gray[1]; byte 516 is x=512 -> gray[510]
    if (tid < NSLOT) {
        g[tid][3]   = g[tid][5];    // 4+1
        g[tid][516] = g[tid][514];  // 4+510
    }
    __syncthreads();

    // Phase 2: sobel on 16 core rows: 16 x 64 segs = 1024 tasks; 4/thread.
    float mn = INFINITY, mx = 0.0f;
    #pragma unroll
    for (int k = 0; k < 4; ++k) {
        int task = tid + k * 256;
        int r  = task >> 6;   // 0..15 -> slots r, r+1, r+2 (center row y0+r)
        int s8 = task & 63;   // 8-px segment
        const uint8_t* rp0 = &g[r][s8 * 8];
        const uint8_t* rp1 = &g[r + 1][s8 * 8];
        const uint8_t* rp2 = &g[r + 2][s8 * 8];
        uint2 a0 = *(const uint2*)rp0, b0 = *(const uint2*)(rp0 + 8);
        uint2 a1 = *(const uint2*)rp1, b1 = *(const uint2*)(rp1 + 8);
        uint2 a2 = *(const uint2*)rp2, b2 = *(const uint2*)(rp2 + 8);
        uint2 qw; qw.x = a1.y; qw.y = b1.x;
        *(uint2*)(q + (size_t)(y0 + r) * W + s8 * 8) = qw;
        float c0[10], c1[10], c2[10];
        cols10(a0, b0, c0);
        cols10(a1, b1, c1);
        cols10(a2, b2, c2);
        float sx[10], sy[10];
        #pragma unroll
        for (int j = 0; j < 10; ++j) {
            sx[j] = c0[j] + 2.0f * c1[j] + c2[j];
            sy[j] = c2[j] - c0[j];
        }
        #pragma unroll
        for (int p = 0; p < 8; ++p) {
            float gx = sx[p + 2] - sx[p];
            float gy = sy[p] + 2.0f * sy[p + 1] + sy[p + 2];
            float m = sqrtf(gx * gx + gy * gy);
            mn = fminf(mn, m);
            mx = fmaxf(mx, m);
        }
    }

    // block reduce + plain store (no atomics)
    #pragma unroll
    for (int o = 32; o > 0; o >>= 1) {
        mn = fminf(mn, __shfl_down(mn, o));
        mx = fmaxf(mx, __shfl_down(mx, o));
    }
    int lane = tid & 63, w = tid >> 6;
    if (lane == 0) { red[w][0] = mn; red[w][1] = mx; }
    __syncthreads();
    if (tid == 0) {
        #pragma unroll
        for (int ww = 1; ww < 4; ++ww) {
            mn = fminf(mn, red[ww][0]);
            mx = fmaxf(mx, red[ww][1]);
        }
        float* o = pm + ((size_t)(src * B + b) * NSTRIP + strip) * 2;
        o[0] = mn;
        o[1] = mx;
    }
}

// Extract this lane's 10 stencil columns from an 8-byte row segment via shuffles.
__device__ __forceinline__ void row_cols(uint2 v, int lane, float* __restrict__ c) {
    uint32_t lx = __shfl_up(v.y, 1);
    uint32_t rx = __shfl_down(v.x, 1);
    uint32_t lb = (lane == 0)  ? ((v.x >> 8) & 0xffu)  : (lx >> 24);
    uint32_t rb = (lane == 63) ? ((v.y >> 16) & 0xffu) : (rx & 0xffu);
    c[0] = (float)lb;
    c[1] = (float)(v.x & 0xffu);
    c[2] = (float)((v.x >> 8) & 0xffu);
    c[3] = (float)((v.x >> 16) & 0xffu);
    c[4] = (float)(v.x >> 24);
    c[5] = (float)(v.y & 0xffu);
    c[6] = (float)((v.y >> 8) & 0xffu);
    c[7] = (float)((v.y >> 16) & 0xffu);
    c[8] = (float)(v.y >> 24);
    c[9] = (float)rb;
}

__device__ __forceinline__ void sobel_row8(const uint8_t* __restrict__ q, int y, int lane,
                                           float* __restrict__ mag) {
    const uint2* rm = (const uint2*)(q + (size_t)refl(y - 1, H) * W);
    const uint2* r0 = (const uint2*)(q + (size_t)y * W);
    const uint2* rp = (const uint2*)(q + (size_t)refl(y + 1, H) * W);
    uint2 vm = rm[lane], v0 = r0[lane], vp = rp[lane];
    float c0[10], c1[10], c2[10];
    row_cols(vm, lane, c0);
    row_cols(v0, lane, c1);
    row_cols(vp, lane, c2);
    float sx[10], sy[10];
    #pragma unroll
    for (int j = 0; j < 10; ++j) {
        sx[j] = c0[j] + 2.0f * c1[j] + c2[j];
        sy[j] = c2[j] - c0[j];
    }
    #pragma unroll
    for (int k = 0; k < 8; ++k) {
        float gx = sx[k + 2] - sx[k];
        float gy = sy[k] + 2.0f * sy[k + 1] + sy[k + 2];
        mag[k] = sqrtf(gx * gx + gy * gy);
    }
}

// ---------------- K2: minmax finalize + weighted blend + |diff| partial sums ----------------
// block = 4 waves; prologue: wave w shuffle-reduces one of {mn_v,mx_v,mn_i,mx_i}
// from the 32 per-strip partials (lane&31: duplicated lanes are idempotent for
// min/max); then each wave handles rows y0+w and y0+w+4. Plain stores only —
// NO agent-scope atomics (they force per-block L2 flushes on multi-XCD parts).
__global__ __launch_bounds__(256) void k_loss(const float* __restrict__ vis,
                                              const float* __restrict__ ir,
                                              const float* __restrict__ fus,
                                              const uint8_t* __restrict__ qvis,
                                              const uint8_t* __restrict__ qir,
                                              const float* __restrict__ pm,
                                              float* __restrict__ partial, int B) {
    int w = threadIdx.x >> 6, lane = threadIdx.x & 63;
    int b = blockIdx.x >> 6;
    int y0 = (blockIdx.x & 63) * 8;

    __shared__ float sred[4];
    {
        int src = w >> 1, qsel = w & 1;
        float v = pm[((size_t)(src * B + b) * NSTRIP + (lane & 31)) * 2 + qsel];
        if (qsel == 0) {
            #pragma unroll
            for (int o = 32; o > 0; o >>= 1) v = fminf(v, __shfl_down(v, o));
        } else {
            #pragma unroll
            for (int o = 32; o > 0; o >>= 1) v = fmaxf(v, __shfl_down(v, o));
        }
        if (lane == 0) sred[w] = v;
    }
    __syncthreads();
    float mn_v = sred[0], mx_v = sred[1], mn_i = sred[2], mx_i = sred[3];
    float inv_v = 1.0f / fmaxf(mx_v - mn_v, 1e-8f);
    float inv_i = 1.0f / fmaxf(mx_i - mn_i, 1e-8f);

    float acc = 0.0f;
    #pragma unroll
    for (int rr = 0; rr < 2; ++rr) {
        int y = y0 + w + rr * 4;
        float mv[8], mi[8];
        sobel_row8(qvis + (size_t)b * HW, y, lane, mv);
        sobel_row8(qir  + (size_t)b * HW, y, lane, mi);

        float wv[8], wi[8];
        #pragma unroll
        for (int k = 0; k < 8; ++k) {
            float sv = (mv[k] - mn_v) * inv_v;
            float si = (mi[k] - mn_i) * inv_i;
            float den = sv + si + 1e-8f;
            float rden = 1.0f / den;
            wv[k] = sv * rden;
            wi[k] = si * rden;
        }

        int i = y * W + lane * 8;
        #pragma unroll
        for (int ch = 0; ch < 3; ++ch) {
            size_t e4 = ((((size_t)b * 3 + ch) * HW) + i) >> 2;
            const float4* v4 = (const float4*)vis;
            const float4* r4 = (const float4*)ir;
            const float4* f4 = (const float4*)fus;
            float4 va = v4[e4], vb = v4[e4 + 1];
            float4 ra = r4[e4], rb = r4[e4 + 1];
            float4 fa = f4[e4], fb = f4[e4 + 1];
            acc += fabsf(wv[0] * va.x + wi[0] * ra.x - fa.x);
            acc += fabsf(wv[1] * va.y + wi[1] * ra.y - fa.y);
            acc += fabsf(wv[2] * va.z + wi[2] * ra.z - fa.z);
            acc += fabsf(wv[3] * va.w + wi[3] * ra.w - fa.w);
            acc += fabsf(wv[4] * vb.x + wi[4] * rb.x - fb.x);
            acc += fabsf(wv[5] * vb.y + wi[5] * rb.y - fb.y);
            acc += fabsf(wv[6] * vb.z + wi[6] * rb.z - fb.z);
            acc += fabsf(wv[7] * vb.w + wi[7] * rb.w - fb.w);
        }
    }

    #pragma unroll
    for (int o = 32; o > 0; o >>= 1) acc += __shfl_down(acc, o);
    __shared__ float ssum[4];
    if (lane == 0) ssum[w] = acc;
    __syncthreads();
    if (threadIdx.x == 0) partial[blockIdx.x] = ssum[0] + ssum[1] + ssum[2] + ssum[3];
}

// ---------------- K3: final reduce ----------------
__global__ void k_final(const float* __restrict__ partial, int n, float* __restrict__ out,
                        long long N) {
    double s = 0.0;
    for (int i = threadIdx.x; i < n; i += 256) s += (double)partial[i];
    __shared__ double sm[256];
    sm[threadIdx.x] = s;
    __syncthreads();
    for (int k = 128; k > 0; k >>= 1) {
        if (threadIdx.x < k) sm[threadIdx.x] += sm[threadIdx.x + k];
        __syncthreads();
    }
    if (threadIdx.x == 0) out[0] = (float)(sm[0] / (double)N);
}

extern "C" void kernel_launch(void* const* d_in, const int* in_sizes, int n_in,
                              void* d_out, int out_size, void* d_ws, size_t ws_size,
                              hipStream_t stream) {
    const float* vis = (const float*)d_in[0];
    const float* ir  = (const float*)d_in[1];
    const float* fus = (const float*)d_in[2];
    int B = in_sizes[0] / (3 * HW);  // 16

    uint8_t* qvis = (uint8_t*)d_ws;
    uint8_t* qir  = qvis + (size_t)B * HW;
    float* pm      = (float*)(qir + (size_t)B * HW);       // 2*B*32*2 floats
    float* partial = pm + (size_t)2 * B * NSTRIP * 2;      // 1024 floats
    float* out = (float*)d_out;

    int nblk_sal = 2 * B * NSTRIP;   // 1024 blocks (one source, 16-row strip each)
    k_sal<<<nblk_sal, 256, 0, stream>>>(vis, ir, qvis, qir, pm, B);

    int nblk_loss = B * (H / 8);     // 1024 blocks
    k_loss<<<nblk_loss, 256, 0, stream>>>(vis, ir, fus, qvis, qir, pm, partial, B);

    k_final<<<1, 256, 0, stream>>>(partial, nblk_loss, out, (long long)B * 3 * HW);
}